// Round 1
// baseline (1146.656 us; speedup 1.0000x reference)
//
#include <hip/hip_runtime.h>
#include <hip/hip_bf16.h>

typedef short short8 __attribute__((ext_vector_type(8)));
typedef float f32x4 __attribute__((ext_vector_type(4)));

#define AS1(p) ((const __attribute__((address_space(1))) void*)(p))
#define AS3(p) ((__attribute__((address_space(3))) void*)(p))

__device__ __forceinline__ ushort f2bf(float f) {
  __hip_bfloat16 h = __float2bfloat16(f);
  return *reinterpret_cast<const ushort*>(&h);
}

__device__ __forceinline__ float silu_f(float v) { return v / (1.f + __expf(-v)); }

// ---------------- LayerNorm (fp32 in) -> bf16 out ----------------
// one block (256 thr) per row; D = NV*1024
template<int NV>
__global__ __launch_bounds__(256) void ln_bf16_k(
    const float* __restrict__ in, const float* __restrict__ sc,
    const float* __restrict__ bi, ushort* __restrict__ out)
{
  const int D = NV * 1024;
  const long row = blockIdx.x;
  const int tx = threadIdx.x;
  const float* p = in + row * (long)D;
  float4 v[NV];
  float s = 0.f, s2 = 0.f;
#pragma unroll
  for (int t = 0; t < NV; ++t) {
    v[t] = *reinterpret_cast<const float4*>(p + t * 1024 + tx * 4);
    s  += v[t].x + v[t].y + v[t].z + v[t].w;
    s2 += v[t].x * v[t].x + v[t].y * v[t].y + v[t].z * v[t].z + v[t].w * v[t].w;
  }
#pragma unroll
  for (int o = 1; o < 64; o <<= 1) { s += __shfl_xor(s, o); s2 += __shfl_xor(s2, o); }
  __shared__ float red[2][4];
  const int wave = tx >> 6;
  if ((tx & 63) == 0) { red[0][wave] = s; red[1][wave] = s2; }
  __syncthreads();
  s  = red[0][0] + red[0][1] + red[0][2] + red[0][3];
  s2 = red[1][0] + red[1][1] + red[1][2] + red[1][3];
  const float mu   = s / D;
  const float rstd = rsqrtf(s2 / D - mu * mu + 1e-6f);
#pragma unroll
  for (int t = 0; t < NV; ++t) {
    const int d = t * 1024 + tx * 4;
    float4 g = *reinterpret_cast<const float4*>(sc + d);
    float4 b = *reinterpret_cast<const float4*>(bi + d);
    ushort4 o;
    o.x = f2bf((v[t].x - mu) * rstd * g.x + b.x);
    o.y = f2bf((v[t].y - mu) * rstd * g.y + b.y);
    o.z = f2bf((v[t].z - mu) * rstd * g.z + b.z);
    o.w = f2bf((v[t].w - mu) * rstd * g.w + b.w);
    *reinterpret_cast<ushort4*>(out + row * (long)D + d) = o;
  }
}

// ---------------- fp32 [K][N] -> bf16 [N][K] (transpose + convert) ----------
// block (64,4), grid (N/64, K/64)
__global__ __launch_bounds__(256) void transpose_bf16_k(
    const float* __restrict__ in, ushort* __restrict__ out, int K, int N)
{
  __shared__ float tile[64][65];
  const int k0 = blockIdx.y * 64, n0 = blockIdx.x * 64;
  const int tx = threadIdx.x, ty = threadIdx.y;
#pragma unroll
  for (int r = ty; r < 64; r += 4)
    tile[r][tx] = in[(long)(k0 + r) * N + n0 + tx];
  __syncthreads();
#pragma unroll
  for (int r = ty; r < 64; r += 4)
    out[(long)(n0 + r) * K + k0 + tx] = f2bf(tile[tx][r]);
}

// ---------------- GEMM: C[M][N] (+bias, +silu, +residual) ------------------
// A [M][K] bf16 row-major, Bt [N][K] bf16 row-major (W transposed).
// 128x128 tile, BK=32, 4 waves (2x2), each wave 64x64 via 4x4 16x16x32 MFMA.
// MODE 0: C = silu(acc+b)   (stem)
// MODE 1: C = C + silu(acc+b)  (residual block, in-place)
// MODE 2: C = acc + b       (head)
template<int MODE>
__global__ __launch_bounds__(256) void gemm_bt_k(
    const ushort* __restrict__ A, const ushort* __restrict__ Bt,
    const float* __restrict__ bias, float* __restrict__ C,
    int M, int N, int K)
{
  __shared__ __align__(16) ushort As[128][32];
  __shared__ __align__(16) ushort Bs[128][32];
  const int tid  = threadIdx.x;
  const int lane = tid & 63, wave = tid >> 6;
  const int nbx = N >> 7;
  const int bx = blockIdx.x % nbx, by = blockIdx.x / nbx;
  const long m0 = (long)by << 7, n0 = (long)bx << 7;
  const int wr = wave >> 1, wc = wave & 1;

  // staging: each wave covers 32 rows (2 issues x 16 rows); lane -> (row, 16B chunk)
  const int chunk = (lane & 3) * 8;
  const ushort* aptr = A  + (m0 + wave * 32 + (lane >> 2)) * K + chunk;
  const ushort* bptr = Bt + (n0 + wave * 32 + (lane >> 2)) * K + chunk;
  ushort* as_base = &As[wave * 32][0];
  ushort* bs_base = &Bs[wave * 32][0];

  f32x4 acc[4][4] = {};

  for (int k0 = 0; k0 < K; k0 += 32) {
    __builtin_amdgcn_global_load_lds(AS1(aptr),            AS3(as_base),           16, 0, 0);
    __builtin_amdgcn_global_load_lds(AS1(aptr + 16L * K),  AS3(as_base + 16 * 32), 16, 0, 0);
    __builtin_amdgcn_global_load_lds(AS1(bptr),            AS3(bs_base),           16, 0, 0);
    __builtin_amdgcn_global_load_lds(AS1(bptr + 16L * K),  AS3(bs_base + 16 * 32), 16, 0, 0);
    aptr += 32; bptr += 32;
    __syncthreads();   // drains vmcnt before barrier (compiler-inserted)

    short8 af[4], bfr[4];
#pragma unroll
    for (int i = 0; i < 4; ++i)
      af[i] = *reinterpret_cast<const short8*>(&As[wr * 64 + i * 16 + (lane & 15)][(lane >> 4) * 8]);
#pragma unroll
    for (int j = 0; j < 4; ++j)
      bfr[j] = *reinterpret_cast<const short8*>(&Bs[wc * 64 + j * 16 + (lane & 15)][(lane >> 4) * 8]);
#pragma unroll
    for (int i = 0; i < 4; ++i)
#pragma unroll
      for (int j = 0; j < 4; ++j)
        acc[i][j] = __builtin_amdgcn_mfma_f32_16x16x32_bf16(af[i], bfr[j], acc[i][j], 0, 0, 0);
    __syncthreads();
  }

  // epilogue: C/D layout col=lane&15, row=(lane>>4)*4+reg  [m89-verified]
#pragma unroll
  for (int j = 0; j < 4; ++j) {
    const long col = n0 + wc * 64 + j * 16 + (lane & 15);
    const float bj = bias[col];
#pragma unroll
    for (int i = 0; i < 4; ++i) {
      const long rowb = m0 + wr * 64 + i * 16 + ((lane >> 4) << 2);
#pragma unroll
      for (int r = 0; r < 4; ++r) {
        float v = acc[i][j][r] + bj;
        const long idx = (rowb + r) * N + col;
        if (MODE == 0)      C[idx] = silu_f(v);
        else if (MODE == 1) C[idx] = C[idx] + silu_f(v);
        else                C[idx] = v;
      }
    }
  }
}

// ---------------------------------------------------------------------------
extern "C" void kernel_launch(void* const* d_in, const int* in_sizes, int n_in,
                              void* d_out, int out_size, void* d_ws, size_t ws_size,
                              hipStream_t stream) {
  const float* x     = (const float*)d_in[0];
  const float* ln1_s = (const float*)d_in[1];
  const float* ln1_b = (const float*)d_in[2];
  const float* w1    = (const float*)d_in[3];
  const float* b1    = (const float*)d_in[4];
  const float* bln_s = (const float*)d_in[5];
  const float* bln_b = (const float*)d_in[6];
  const float* bws   = (const float*)d_in[7];
  const float* bbs   = (const float*)d_in[8];
  const float* ln2_s = (const float*)d_in[9];
  const float* ln2_b = (const float*)d_in[10];
  const float* w2    = (const float*)d_in[11];
  const float* b2    = (const float*)d_in[12];
  float* out = (float*)d_out;

  const int M = 8192;  // 4*2048 tokens
  char* ws = (char*)d_ws;
  float*  h   = (float*)ws;                                   // 8192x2048 f32 = 64MB
  ushort* Abf = (ushort*)(ws + 67108864);                     // 8192x2048 bf16 = 32MB
  ushort* wt  = (ushort*)(ws + 67108864 + 33554432);          // bf16 weights^T, 58.7MB
  const long W1T = 0;                        // [2048][1024]
  const long BLK = 2097152;                  // 6 x [2048][2048]
  const long W2T = BLK + 6L * 4194304;       // [1024][2048]

  dim3 tb(64, 4);
  // weights: fp32 [K][N] -> bf16 [N][K]
  transpose_bf16_k<<<dim3(2048 / 64, 1024 / 64), tb, 0, stream>>>(w1, wt + W1T, 1024, 2048);
  for (int i = 0; i < 6; ++i)
    transpose_bf16_k<<<dim3(32, 32), tb, 0, stream>>>(
        bws + (long)i * 2048 * 2048, wt + BLK + (long)i * 4194304, 2048, 2048);
  transpose_bf16_k<<<dim3(1024 / 64, 2048 / 64), tb, 0, stream>>>(w2, wt + W2T, 2048, 1024);

  // stem: h = silu(LN(x) @ w1 + b1)
  ln_bf16_k<1><<<M, 256, 0, stream>>>(x, ln1_s, ln1_b, Abf);
  gemm_bt_k<0><<<(M / 128) * (2048 / 128), 256, 0, stream>>>(Abf, wt + W1T, b1, h, M, 2048, 1024);

  // residual blocks: h = h + silu(LN(h) @ w[i] + lb[i])
  for (int i = 0; i < 6; ++i) {
    ln_bf16_k<2><<<M, 256, 0, stream>>>(h, bln_s + i * 2048, bln_b + i * 2048, Abf);
    gemm_bt_k<1><<<(M / 128) * (2048 / 128), 256, 0, stream>>>(
        Abf, wt + BLK + (long)i * 4194304, bbs + i * 2048, h, M, 2048, 2048);
  }

  // head: out = LN(h) @ w2 + b2
  ln_bf16_k<2><<<M, 256, 0, stream>>>(h, ln2_s, ln2_b, Abf);
  gemm_bt_k<2><<<(M / 128) * (1024 / 128), 256, 0, stream>>>(Abf, wt + W2T, b2, out, M, 1024, 2048);
}

// Round 2
// 807.910 us; speedup vs baseline: 1.4193x; 1.4193x over previous
//
#include <hip/hip_runtime.h>
#include <hip/hip_bf16.h>

typedef short short8 __attribute__((ext_vector_type(8)));
typedef float f32x4 __attribute__((ext_vector_type(4)));

#define AS1(p) ((const __attribute__((address_space(1))) void*)(p))
#define AS3(p) ((__attribute__((address_space(3))) void*)(p))

__device__ __forceinline__ ushort f2bf(float f) {
  __hip_bfloat16 h = __float2bfloat16(f);
  return *reinterpret_cast<const ushort*>(&h);
}

__device__ __forceinline__ float silu_f(float v) { return v / (1.f + __expf(-v)); }

// ---------------- LayerNorm (fp32 in) -> bf16 out ----------------
template<int NV>
__global__ __launch_bounds__(256) void ln_bf16_k(
    const float* __restrict__ in, const float* __restrict__ sc,
    const float* __restrict__ bi, ushort* __restrict__ out)
{
  const int D = NV * 1024;
  const long row = blockIdx.x;
  const int tx = threadIdx.x;
  const float* p = in + row * (long)D;
  float4 v[NV];
  float s = 0.f, s2 = 0.f;
#pragma unroll
  for (int t = 0; t < NV; ++t) {
    v[t] = *reinterpret_cast<const float4*>(p + t * 1024 + tx * 4);
    s  += v[t].x + v[t].y + v[t].z + v[t].w;
    s2 += v[t].x * v[t].x + v[t].y * v[t].y + v[t].z * v[t].z + v[t].w * v[t].w;
  }
#pragma unroll
  for (int o = 1; o < 64; o <<= 1) { s += __shfl_xor(s, o); s2 += __shfl_xor(s2, o); }
  __shared__ float red[2][4];
  const int wave = tx >> 6;
  if ((tx & 63) == 0) { red[0][wave] = s; red[1][wave] = s2; }
  __syncthreads();
  s  = red[0][0] + red[0][1] + red[0][2] + red[0][3];
  s2 = red[1][0] + red[1][1] + red[1][2] + red[1][3];
  const float mu   = s / D;
  const float rstd = rsqrtf(s2 / D - mu * mu + 1e-6f);
#pragma unroll
  for (int t = 0; t < NV; ++t) {
    const int d = t * 1024 + tx * 4;
    float4 g = *reinterpret_cast<const float4*>(sc + d);
    float4 b = *reinterpret_cast<const float4*>(bi + d);
    ushort4 o;
    o.x = f2bf((v[t].x - mu) * rstd * g.x + b.x);
    o.y = f2bf((v[t].y - mu) * rstd * g.y + b.y);
    o.z = f2bf((v[t].z - mu) * rstd * g.z + b.z);
    o.w = f2bf((v[t].w - mu) * rstd * g.w + b.w);
    *reinterpret_cast<ushort4*>(out + row * (long)D + d) = o;
  }
}

// ---------------- fp32 [K][N] -> bf16 [N][K] (transpose + convert) ----------
__global__ __launch_bounds__(256) void transpose_bf16_k(
    const float* __restrict__ in, ushort* __restrict__ out, int K, int N)
{
  __shared__ float tile[64][65];
  const int k0 = blockIdx.y * 64, n0 = blockIdx.x * 64;
  const int tx = threadIdx.x, ty = threadIdx.y;
#pragma unroll
  for (int r = ty; r < 64; r += 4)
    tile[r][tx] = in[(long)(k0 + r) * N + n0 + tx];
  __syncthreads();
#pragma unroll
  for (int r = ty; r < 64; r += 4)
    out[(long)(n0 + r) * K + k0 + tx] = f2bf(tile[tx][r]);
}

// ============================================================================
// 256x256 8-phase GEMM: C[M][N] = A[M][K] @ Bt[N][K]^T  (+bias, +silu, +res)
// 512 threads = 8 waves (2Mx4N); per-wave 128x64 output; BK=64.
// LDS 128 KiB dynamic: [dbuf][A|B][half][128 rows][64 k] bf16, XOR-swizzled.
// MODE 0: C = silu(acc+b);  MODE 1: C += silu(acc+b);  MODE 2: C = acc+b.
// ============================================================================
#define STAGE_HT(dbuf, mat, half, kt, base)                                     \
  {                                                                             \
    const ushort* g0_ = (base) + (half) * offH + (long)(kt) * 64;               \
    char* l0_ = ldsW + (dbuf) * 65536 + (mat) * 32768 + (half) * 16384;         \
    __builtin_amdgcn_global_load_lds(AS1(g0_),        AS3(l0_),        16, 0, 0); \
    __builtin_amdgcn_global_load_lds(AS1(g0_ + offQ), AS3(l0_ + 8192), 16, 0, 0); \
  }

#define LOAD_A(dst, dbuf, ihalf)                                                \
  _Pragma("unroll") for (int i_ = 0; i_ < 4; ++i_) {                            \
    dst[i_][0] = *(const short8*)(smem + (dbuf) * 65536 + aOff + ((ihalf) * 4 + i_) * 2048 + rdk0); \
    dst[i_][1] = *(const short8*)(smem + (dbuf) * 65536 + aOff + ((ihalf) * 4 + i_) * 2048 + rdk1); \
  }

#define LOAD_B(dst, dbuf, jhalf)                                                \
  _Pragma("unroll") for (int j_ = 0; j_ < 2; ++j_) {                            \
    dst[j_][0] = *(const short8*)(smem + (dbuf) * 65536 + bOff + ((jhalf) * 2 + j_) * 2048 + rdk0); \
    dst[j_][1] = *(const short8*)(smem + (dbuf) * 65536 + bOff + ((jhalf) * 2 + j_) * 2048 + rdk1); \
  }

#define MFMA_Q(ihalf, jhalf, afr, bfr)                                          \
  __builtin_amdgcn_s_setprio(1);                                                \
  _Pragma("unroll") for (int i_ = 0; i_ < 4; ++i_)                              \
  _Pragma("unroll") for (int j_ = 0; j_ < 2; ++j_)                              \
  _Pragma("unroll") for (int kk_ = 0; kk_ < 2; ++kk_)                           \
    acc[(ihalf) * 4 + i_][(jhalf) * 2 + j_] =                                   \
        __builtin_amdgcn_mfma_f32_16x16x32_bf16(afr[i_][kk_], bfr[j_][kk_],     \
            acc[(ihalf) * 4 + i_][(jhalf) * 2 + j_], 0, 0, 0);                  \
  __builtin_amdgcn_s_setprio(0);

template<int MODE>
__global__ __launch_bounds__(512, 2) void gemm256_k(
    const ushort* __restrict__ A, const ushort* __restrict__ Bt,
    const float* __restrict__ bias, float* __restrict__ C,
    int M, int N, int K)
{
  extern __shared__ char smem[];
  const int tid = threadIdx.x;
  const int lane = tid & 63, wid = tid >> 6;
  const int wr = wid >> 2, wc = wid & 3;
  const int nbx = N >> 8;

  // bijective XCD swizzle: each XCD gets a contiguous chunk of tile-rows
  int bid;
  {
    const int b = blockIdx.x;
    const int cpx = gridDim.x >> 3;
    bid = (b & 7) * cpx + (b >> 3);
  }
  const int bx = bid % nbx, by = bid / nbx;
  const long m0 = (long)by << 8, n0 = (long)bx << 8;

  // staging geometry: thread -> (row q*64 + tid>>3, swizzled 16B chunk)
  const int srow = tid >> 3;
  const int scol = (((tid & 7) * 16) ^ (((tid >> 3) & 7) << 4)) >> 1;  // elements
  const ushort* aBase = A  + (m0 + srow) * (long)K + scol;
  const ushort* bBase = Bt + (n0 + srow) * (long)K + scol;
  const long offH = 128L * K, offQ = 64L * K;
  char* ldsW = smem + wid * 1024;

  // ds_read fragment offsets (bytes); XOR swizzle ((row&7)<<4) == ((lane&7)<<4)
  const int rdk0 = (((lane >> 4) * 16)      ) ^ ((lane & 7) << 4);
  const int rdk1 = (((lane >> 4) * 16) + 64 ) ^ ((lane & 7) << 4);
  const int aOff = wr * 16384 + (lane & 15) * 128;
  const int bOff = 32768 + (wc >> 1) * 16384 + ((wc & 1) * 64 + (lane & 15)) * 128;

  f32x4 acc[8][4] = {};
  const int NT = K >> 6;

  // prologue: stage t0.B(h0,h1), t0.A(h0,h1), t1.B(h0,h1)  [12 loads]
  STAGE_HT(0, 1, 0, 0, bBase); STAGE_HT(0, 1, 1, 0, bBase);
  STAGE_HT(0, 0, 0, 0, aBase); STAGE_HT(0, 0, 1, 0, aBase);
  STAGE_HT(1, 1, 0, 1, bBase); STAGE_HT(1, 1, 1, 1, bBase);
  asm volatile("s_waitcnt vmcnt(4)" ::: "memory");  // t0 complete; t1.B in flight
  __builtin_amdgcn_sched_barrier(0);
  __builtin_amdgcn_s_barrier();

  short8 af[4][2], bf0[2][2], bf1[2][2];
  for (int t = 0; t < NT; ++t) {
    const int cur = t & 1, nxt = cur ^ 1;
    // ---- P0: read A half0 + B n-half0; stage (t+1).A h0 ----
    LOAD_A(af, cur, 0);
    LOAD_B(bf0, cur, 0);
    if (t + 1 < NT) STAGE_HT(nxt, 0, 0, t + 1, aBase);
    __builtin_amdgcn_s_barrier();
    MFMA_Q(0, 0, af, bf0);
    __builtin_amdgcn_s_barrier();
    // ---- P1: read B n-half1; stage (t+1).A h1 ----
    LOAD_B(bf1, cur, 1);
    if (t + 1 < NT) STAGE_HT(nxt, 0, 1, t + 1, aBase);
    __builtin_amdgcn_s_barrier();
    MFMA_Q(0, 1, af, bf1);
    __builtin_amdgcn_s_barrier();
    // ---- P2: read A half1; stage (t+2).B h0 (cur B fully read) ----
    LOAD_A(af, cur, 1);
    if (t + 2 < NT) STAGE_HT(cur, 1, 0, t + 2, bBase);
    __builtin_amdgcn_s_barrier();
    MFMA_Q(1, 1, af, bf1);
    __builtin_amdgcn_s_barrier();
    // ---- P3: stage (t+2).B h1; counted vmcnt; MFMA ----
    if (t + 2 < NT) {
      STAGE_HT(cur, 1, 1, t + 2, bBase);
      asm volatile("s_waitcnt vmcnt(4)" ::: "memory");  // (t+1) ready; (t+2).B in flight
    } else {
      asm volatile("s_waitcnt vmcnt(0)" ::: "memory");
    }
    __builtin_amdgcn_sched_barrier(0);
    __builtin_amdgcn_s_barrier();
    MFMA_Q(1, 0, af, bf0);
    __builtin_amdgcn_s_barrier();
  }

  // epilogue: C/D layout col=lane&15, row=(lane>>4)*4+reg
#pragma unroll
  for (int j = 0; j < 4; ++j) {
    const long col = n0 + wc * 64 + j * 16 + (lane & 15);
    const float bj = bias[col];
#pragma unroll
    for (int i = 0; i < 8; ++i) {
      const long rowb = m0 + wr * 128 + i * 16 + ((lane >> 4) << 2);
#pragma unroll
      for (int r = 0; r < 4; ++r) {
        float v = acc[i][j][r] + bj;
        const long idx = (rowb + r) * N + col;
        if (MODE == 0)      C[idx] = silu_f(v);
        else if (MODE == 1) C[idx] = C[idx] + silu_f(v);
        else                C[idx] = v;
      }
    }
  }
}

// ---------------------------------------------------------------------------
extern "C" void kernel_launch(void* const* d_in, const int* in_sizes, int n_in,
                              void* d_out, int out_size, void* d_ws, size_t ws_size,
                              hipStream_t stream) {
  const float* x     = (const float*)d_in[0];
  const float* ln1_s = (const float*)d_in[1];
  const float* ln1_b = (const float*)d_in[2];
  const float* w1    = (const float*)d_in[3];
  const float* b1    = (const float*)d_in[4];
  const float* bln_s = (const float*)d_in[5];
  const float* bln_b = (const float*)d_in[6];
  const float* bws   = (const float*)d_in[7];
  const float* bbs   = (const float*)d_in[8];
  const float* ln2_s = (const float*)d_in[9];
  const float* ln2_b = (const float*)d_in[10];
  const float* w2    = (const float*)d_in[11];
  const float* b2    = (const float*)d_in[12];
  float* out = (float*)d_out;

  const int M = 8192;
  char* ws = (char*)d_ws;
  float*  h   = (float*)ws;                                   // 8192x2048 f32
  ushort* Abf = (ushort*)(ws + 67108864);                     // 8192x2048 bf16
  ushort* wt  = (ushort*)(ws + 67108864 + 33554432);          // bf16 weights^T
  const long W1T = 0;
  const long BLK = 2097152;
  const long W2T = BLK + 6L * 4194304;

  (void)hipFuncSetAttribute((const void*)gemm256_k<0>,
      hipFuncAttributeMaxDynamicSharedMemorySize, 131072);
  (void)hipFuncSetAttribute((const void*)gemm256_k<1>,
      hipFuncAttributeMaxDynamicSharedMemorySize, 131072);
  (void)hipFuncSetAttribute((const void*)gemm256_k<2>,
      hipFuncAttributeMaxDynamicSharedMemorySize, 131072);

  dim3 tb(64, 4);
  transpose_bf16_k<<<dim3(2048 / 64, 1024 / 64), tb, 0, stream>>>(w1, wt + W1T, 1024, 2048);
  for (int i = 0; i < 6; ++i)
    transpose_bf16_k<<<dim3(32, 32), tb, 0, stream>>>(
        bws + (long)i * 2048 * 2048, wt + BLK + (long)i * 4194304, 2048, 2048);
  transpose_bf16_k<<<dim3(1024 / 64, 2048 / 64), tb, 0, stream>>>(w2, wt + W2T, 2048, 1024);

  // stem: h = silu(LN(x) @ w1 + b1)      (M/256=32, N/256=8 -> 256 WGs)
  ln_bf16_k<1><<<M, 256, 0, stream>>>(x, ln1_s, ln1_b, Abf);
  gemm256_k<0><<<32 * 8, 512, 131072, stream>>>(Abf, wt + W1T, b1, h, M, 2048, 1024);

  // residual blocks: h = h + silu(LN(h) @ w[i] + lb[i])
  for (int i = 0; i < 6; ++i) {
    ln_bf16_k<2><<<M, 256, 0, stream>>>(h, bln_s + i * 2048, bln_b + i * 2048, Abf);
    gemm256_k<1><<<32 * 8, 512, 131072, stream>>>(
        Abf, wt + BLK + (long)i * 4194304, bbs + i * 2048, h, M, 2048, 2048);
  }

  // head: out = LN(h) @ w2 + b2          (32 x 4 = 128 WGs)
  ln_bf16_k<2><<<M, 256, 0, stream>>>(h, ln2_s, ln2_b, Abf);
  gemm256_k<2><<<32 * 4, 512, 131072, stream>>>(Abf, wt + W2T, b2, out, M, 1024, 2048);
}

// Round 3
// 798.340 us; speedup vs baseline: 1.4363x; 1.0120x over previous
//
#include <hip/hip_runtime.h>
#include <hip/hip_bf16.h>

typedef short short8 __attribute__((ext_vector_type(8)));
typedef float f32x4 __attribute__((ext_vector_type(4)));

#define AS1(p) ((const __attribute__((address_space(1))) void*)(p))
#define AS3(p) ((__attribute__((address_space(3))) void*)(p))

__device__ __forceinline__ ushort f2bf(float f) {
  __hip_bfloat16 h = __float2bfloat16(f);
  return *reinterpret_cast<const ushort*>(&h);
}

__device__ __forceinline__ float silu_f(float v) { return v / (1.f + __expf(-v)); }

// ---------------- LayerNorm (fp32 in) -> bf16 out ----------------
template<int NV>
__global__ __launch_bounds__(256) void ln_bf16_k(
    const float* __restrict__ in, const float* __restrict__ sc,
    const float* __restrict__ bi, ushort* __restrict__ out)
{
  const int D = NV * 1024;
  const long row = blockIdx.x;
  const int tx = threadIdx.x;
  const float* p = in + row * (long)D;
  float4 v[NV];
  float s = 0.f, s2 = 0.f;
#pragma unroll
  for (int t = 0; t < NV; ++t) {
    v[t] = *reinterpret_cast<const float4*>(p + t * 1024 + tx * 4);
    s  += v[t].x + v[t].y + v[t].z + v[t].w;
    s2 += v[t].x * v[t].x + v[t].y * v[t].y + v[t].z * v[t].z + v[t].w * v[t].w;
  }
#pragma unroll
  for (int o = 1; o < 64; o <<= 1) { s += __shfl_xor(s, o); s2 += __shfl_xor(s2, o); }
  __shared__ float red[2][4];
  const int wave = tx >> 6;
  if ((tx & 63) == 0) { red[0][wave] = s; red[1][wave] = s2; }
  __syncthreads();
  s  = red[0][0] + red[0][1] + red[0][2] + red[0][3];
  s2 = red[1][0] + red[1][1] + red[1][2] + red[1][3];
  const float mu   = s / D;
  const float rstd = rsqrtf(s2 / D - mu * mu + 1e-6f);
#pragma unroll
  for (int t = 0; t < NV; ++t) {
    const int d = t * 1024 + tx * 4;
    float4 g = *reinterpret_cast<const float4*>(sc + d);
    float4 b = *reinterpret_cast<const float4*>(bi + d);
    ushort4 o;
    o.x = f2bf((v[t].x - mu) * rstd * g.x + b.x);
    o.y = f2bf((v[t].y - mu) * rstd * g.y + b.y);
    o.z = f2bf((v[t].z - mu) * rstd * g.z + b.z);
    o.w = f2bf((v[t].w - mu) * rstd * g.w + b.w);
    *reinterpret_cast<ushort4*>(out + row * (long)D + d) = o;
  }
}

// ---------------- fp32 [K][N] -> bf16 [N][K] (transpose + convert) ----------
__global__ __launch_bounds__(256) void transpose_bf16_k(
    const float* __restrict__ in, ushort* __restrict__ out, int K, int N)
{
  __shared__ float tile[64][65];
  const int k0 = blockIdx.y * 64, n0 = blockIdx.x * 64;
  const int tx = threadIdx.x, ty = threadIdx.y;
#pragma unroll
  for (int r = ty; r < 64; r += 4)
    tile[r][tx] = in[(long)(k0 + r) * N + n0 + tx];
  __syncthreads();
#pragma unroll
  for (int r = ty; r < 64; r += 4)
    out[(long)(n0 + r) * K + k0 + tx] = f2bf(tile[tx][r]);
}

// ============================================================================
// 256x256 8-phase GEMM, 2 K-tiles per iteration (literal double-buffer index).
// 512 thr = 8 waves (2Mx4N), per-wave 128x64 out, BK=64, LDS 128 KiB,
// XOR-swizzled. Staging rotation (1 half-tile per phase, 3 half-tiles in
// flight, vmcnt(6) once per K-tile — m201/T3+T4 schedule):
//   P0: A(t+1)sh1   P1: -   P2: B(t+2)sh0   P3: B(t+2)sh1 + A(t+2)sh0, vmcnt(6)
// MODE 0: C = silu(acc+b);  MODE 1: C += silu(acc+b);  MODE 2: C = acc+b.
// ============================================================================
#define STG(gsrc, ldst)                                                          \
  __builtin_amdgcn_global_load_lds(AS1(gsrc),          AS3(ldst),        16, 0, 0); \
  __builtin_amdgcn_global_load_lds(AS1((gsrc) + offQ), AS3((ldst) + 8192), 16, 0, 0);

#define ldsA(B, H) (ldsW + (B) * 65536 + (H) * 16384)
#define ldsB(B, H) (ldsW + (B) * 65536 + 32768 + (H) * 16384)

#define LOAD_A(dst, DB, ihalf)                                                  \
  _Pragma("unroll") for (int i_ = 0; i_ < 4; ++i_) {                            \
    dst[i_][0] = *(const short8*)(smem + (DB) * 65536 + aOff + ((ihalf) * 4 + i_) * 2048 + rdk0); \
    dst[i_][1] = *(const short8*)(smem + (DB) * 65536 + aOff + ((ihalf) * 4 + i_) * 2048 + rdk1); \
  }

#define LOAD_B(dst, DB, jhalf)                                                  \
  _Pragma("unroll") for (int j_ = 0; j_ < 2; ++j_) {                            \
    dst[j_][0] = *(const short8*)(smem + (DB) * 65536 + bOff + ((jhalf) * 2 + j_) * 2048 + rdk0); \
    dst[j_][1] = *(const short8*)(smem + (DB) * 65536 + bOff + ((jhalf) * 2 + j_) * 2048 + rdk1); \
  }

// kk outermost: dependent accumulator updates are 8 instructions apart
#define MFMA_Q(ihalf, jhalf, afr, bfr)                                          \
  __builtin_amdgcn_s_setprio(1);                                                \
  _Pragma("unroll") for (int kk_ = 0; kk_ < 2; ++kk_)                           \
  _Pragma("unroll") for (int i_ = 0; i_ < 4; ++i_)                              \
  _Pragma("unroll") for (int j_ = 0; j_ < 2; ++j_)                              \
    acc[(ihalf) * 4 + i_][(jhalf) * 2 + j_] =                                   \
        __builtin_amdgcn_mfma_f32_16x16x32_bf16(afr[i_][kk_], bfr[j_][kk_],     \
            acc[(ihalf) * 4 + i_][(jhalf) * 2 + j_], 0, 0, 0);                  \
  __builtin_amdgcn_s_setprio(0);

// One K-tile = 4 phases. CUR/NXT/offsets/flags are compile-time literals.
#define DO_TILE(CUR, NXT, AO1, AO2, BO2, S0, S2, S3, TAILW)                     \
  LOAD_A(af, CUR, 0);                                                           \
  LOAD_B(bf0, CUR, 0);                                                          \
  if (S0) { STG(aP + (AO1) + offH, ldsA(NXT, 1)); }                             \
  __builtin_amdgcn_s_barrier();                                                 \
  MFMA_Q(0, 0, af, bf0);                                                        \
  __builtin_amdgcn_s_barrier();                                                 \
  LOAD_B(bf1, CUR, 1);                                                          \
  __builtin_amdgcn_s_barrier();                                                 \
  MFMA_Q(0, 1, af, bf1);                                                        \
  __builtin_amdgcn_s_barrier();                                                 \
  LOAD_A(af, CUR, 1);                                                           \
  if (S2) { STG(bP + (BO2), ldsB(CUR, 0)); }                                    \
  __builtin_amdgcn_s_barrier();                                                 \
  MFMA_Q(1, 1, af, bf1);                                                        \
  __builtin_amdgcn_s_barrier();                                                 \
  if (S3) { STG(bP + (BO2) + offH, ldsB(CUR, 1)); STG(aP + (AO2), ldsA(CUR, 0)); } \
  if (S3)            { asm volatile("s_waitcnt vmcnt(6)" ::: "memory"); }       \
  else if (TAILW)    { asm volatile("s_waitcnt vmcnt(0)" ::: "memory"); }       \
  __builtin_amdgcn_sched_barrier(0);                                            \
  __builtin_amdgcn_s_barrier();                                                 \
  MFMA_Q(1, 0, af, bf0);                                                        \
  __builtin_amdgcn_s_barrier();

template<int MODE>
__global__ __launch_bounds__(512, 2) void gemm256_k(
    const ushort* __restrict__ A, const ushort* __restrict__ Bt,
    const float* __restrict__ bias, float* __restrict__ C,
    int M, int N, int K)
{
  extern __shared__ char smem[];
  const int tid = threadIdx.x;
  const int lane = tid & 63, wid = tid >> 6;
  const int wr = wid >> 2, wc = wid & 3;
  const int nbx = N >> 8;

  // bijective XCD swizzle (grid % 8 == 0 for all shapes here)
  int bid;
  {
    const int b = blockIdx.x;
    const int cpx = gridDim.x >> 3;
    bid = (b & 7) * cpx + (b >> 3);
  }
  const int bx = bid % nbx, by = bid / nbx;
  const long m0 = (long)by << 8, n0 = (long)bx << 8;

  // staging: thread -> (row tid>>3 [+64], inverse-swizzled 16B chunk)
  const int srow = tid >> 3;
  const int scol = (((tid & 7) * 16) ^ (((tid >> 3) & 7) << 4)) >> 1;  // elements
  const ushort* aP = A  + (m0 + srow) * (long)K + scol;
  const ushort* bP = Bt + (n0 + srow) * (long)K + scol;
  const long offH = 128L * K, offQ = 64L * K;
  char* ldsW = smem + wid * 1024;

  // ds_read offsets (bytes); XOR swizzle ((row&7)<<4) == ((lane&7)<<4)
  const int rdk0 = (((lane >> 4) * 16)     ) ^ ((lane & 7) << 4);
  const int rdk1 = (((lane >> 4) * 16) + 64) ^ ((lane & 7) << 4);
  const int aOff = wr * 16384 + (lane & 15) * 128;
  const int bOff = 32768 + (wc >> 1) * 16384 + ((wc & 1) * 64 + (lane & 15)) * 128;

  f32x4 acc[8][4] = {};
  const int NT = K >> 6;  // even (>= 16) for all shapes here

  // prologue: 14 loads; vmcnt(6) leaves B(1) + A(1)sh0 in flight (steady state)
  STG(aP,           ldsA(0, 0));  STG(aP + offH,      ldsA(0, 1));
  STG(bP,           ldsB(0, 0));  STG(bP + offH,      ldsB(0, 1));
  STG(bP + 64,      ldsB(1, 0));  STG(bP + 64 + offH, ldsB(1, 1));
  STG(aP + 64,      ldsA(1, 0));
  asm volatile("s_waitcnt vmcnt(6)" ::: "memory");
  __builtin_amdgcn_sched_barrier(0);
  __builtin_amdgcn_s_barrier();

  short8 af[4][2], bf0[2][2], bf1[2][2];
  for (int t = 0; t < NT - 2; t += 2) {
    DO_TILE(0, 1,  64, 128, 128, 1, 1, 1, 0)
    DO_TILE(1, 0, 128, 192, 192, 1, 1, 1, 0)
    aP += 128; bP += 128;
  }
  // tail pair (tiles NT-2, NT-1): only A(NT-1)sh1 still to stage
  DO_TILE(0, 1, 64, 0, 0, 1, 0, 0, 1)
  DO_TILE(1, 0,  0, 0, 0, 0, 0, 0, 0)

  // epilogue: C/D layout col=lane&15, row=(lane>>4)*4+reg
#pragma unroll
  for (int j = 0; j < 4; ++j) {
    const long col = n0 + wc * 64 + j * 16 + (lane & 15);
    const float bj = bias[col];
#pragma unroll
    for (int i = 0; i < 8; ++i) {
      const long rowb = m0 + wr * 128 + i * 16 + ((lane >> 4) << 2);
#pragma unroll
      for (int r = 0; r < 4; ++r) {
        float v = acc[i][j][r] + bj;
        const long idx = (rowb + r) * N + col;
        if (MODE == 0)      C[idx] = silu_f(v);
        else if (MODE == 1) C[idx] = C[idx] + silu_f(v);
        else                C[idx] = v;
      }
    }
  }
}

// ---------------------------------------------------------------------------
extern "C" void kernel_launch(void* const* d_in, const int* in_sizes, int n_in,
                              void* d_out, int out_size, void* d_ws, size_t ws_size,
                              hipStream_t stream) {
  const float* x     = (const float*)d_in[0];
  const float* ln1_s = (const float*)d_in[1];
  const float* ln1_b = (const float*)d_in[2];
  const float* w1    = (const float*)d_in[3];
  const float* b1    = (const float*)d_in[4];
  const float* bln_s = (const float*)d_in[5];
  const float* bln_b = (const float*)d_in[6];
  const float* bws   = (const float*)d_in[7];
  const float* bbs   = (const float*)d_in[8];
  const float* ln2_s = (const float*)d_in[9];
  const float* ln2_b = (const float*)d_in[10];
  const float* w2    = (const float*)d_in[11];
  const float* b2    = (const float*)d_in[12];
  float* out = (float*)d_out;

  const int M = 8192;
  char* ws = (char*)d_ws;
  float*  h   = (float*)ws;                                   // 8192x2048 f32
  ushort* Abf = (ushort*)(ws + 67108864);                     // 8192x2048 bf16
  ushort* wt  = (ushort*)(ws + 67108864 + 33554432);          // bf16 weights^T
  const long W1T = 0;
  const long BLK = 2097152;
  const long W2T = BLK + 6L * 4194304;

  (void)hipFuncSetAttribute((const void*)gemm256_k<0>,
      hipFuncAttributeMaxDynamicSharedMemorySize, 131072);
  (void)hipFuncSetAttribute((const void*)gemm256_k<1>,
      hipFuncAttributeMaxDynamicSharedMemorySize, 131072);
  (void)hipFuncSetAttribute((const void*)gemm256_k<2>,
      hipFuncAttributeMaxDynamicSharedMemorySize, 131072);

  dim3 tb(64, 4);
  transpose_bf16_k<<<dim3(2048 / 64, 1024 / 64), tb, 0, stream>>>(w1, wt + W1T, 1024, 2048);
  for (int i = 0; i < 6; ++i)
    transpose_bf16_k<<<dim3(32, 32), tb, 0, stream>>>(
        bws + (long)i * 2048 * 2048, wt + BLK + (long)i * 4194304, 2048, 2048);
  transpose_bf16_k<<<dim3(1024 / 64, 2048 / 64), tb, 0, stream>>>(w2, wt + W2T, 2048, 1024);

  // stem: h = silu(LN(x) @ w1 + b1)
  ln_bf16_k<1><<<M, 256, 0, stream>>>(x, ln1_s, ln1_b, Abf);
  gemm256_k<0><<<32 * 8, 512, 131072, stream>>>(Abf, wt + W1T, b1, h, M, 2048, 1024);

  // residual blocks: h = h + silu(LN(h) @ w[i] + lb[i])
  for (int i = 0; i < 6; ++i) {
    ln_bf16_k<2><<<M, 256, 0, stream>>>(h, bln_s + i * 2048, bln_b + i * 2048, Abf);
    gemm256_k<1><<<32 * 8, 512, 131072, stream>>>(
        Abf, wt + BLK + (long)i * 4194304, bbs + i * 2048, h, M, 2048, 2048);
  }

  // head: out = LN(h) @ w2 + b2
  ln_bf16_k<2><<<M, 256, 0, stream>>>(h, ln2_s, ln2_b, Abf);
  gemm256_k<2><<<32 * 4, 512, 131072, stream>>>(Abf, wt + W2T, b2, out, M, 1024, 2048);
}

// Round 4
// 755.751 us; speedup vs baseline: 1.5172x; 1.0564x over previous
//
#include <hip/hip_runtime.h>
#include <hip/hip_bf16.h>

typedef short short8 __attribute__((ext_vector_type(8)));
typedef float f32x4 __attribute__((ext_vector_type(4)));

#define AS1(p) ((const __attribute__((address_space(1))) void*)(p))
#define AS3(p) ((__attribute__((address_space(3))) void*)(p))

__device__ __forceinline__ ushort f2bf(float f) {
  __hip_bfloat16 h = __float2bfloat16(f);
  return *reinterpret_cast<const ushort*>(&h);
}
__device__ __forceinline__ float bfu2f(ushort u) {
  unsigned int x = ((unsigned int)u) << 16;
  float f;
  __builtin_memcpy(&f, &x, 4);
  return f;
}
__device__ __forceinline__ float silu_f(float v) { return v / (1.f + __expf(-v)); }

// ---------------- LayerNorm fp32-in -> bf16 out (stem, D = NV*1024) --------
template<int NV>
__global__ __launch_bounds__(256) void ln_bf16_k(
    const float* __restrict__ in, const float* __restrict__ sc,
    const float* __restrict__ bi, ushort* __restrict__ out)
{
  const int D = NV * 1024;
  const long row = blockIdx.x;
  const int tx = threadIdx.x;
  const float* p = in + row * (long)D;
  float4 v[NV];
  float s = 0.f, s2 = 0.f;
#pragma unroll
  for (int t = 0; t < NV; ++t) {
    v[t] = *reinterpret_cast<const float4*>(p + t * 1024 + tx * 4);
    s  += v[t].x + v[t].y + v[t].z + v[t].w;
    s2 += v[t].x * v[t].x + v[t].y * v[t].y + v[t].z * v[t].z + v[t].w * v[t].w;
  }
#pragma unroll
  for (int o = 1; o < 64; o <<= 1) { s += __shfl_xor(s, o); s2 += __shfl_xor(s2, o); }
  __shared__ float red[2][4];
  const int wave = tx >> 6;
  if ((tx & 63) == 0) { red[0][wave] = s; red[1][wave] = s2; }
  __syncthreads();
  s  = red[0][0] + red[0][1] + red[0][2] + red[0][3];
  s2 = red[1][0] + red[1][1] + red[1][2] + red[1][3];
  const float mu   = s / D;
  const float rstd = rsqrtf(s2 / D - mu * mu + 1e-6f);
#pragma unroll
  for (int t = 0; t < NV; ++t) {
    const int d = t * 1024 + tx * 4;
    float4 g = *reinterpret_cast<const float4*>(sc + d);
    float4 b = *reinterpret_cast<const float4*>(bi + d);
    ushort4 o;
    o.x = f2bf((v[t].x - mu) * rstd * g.x + b.x);
    o.y = f2bf((v[t].y - mu) * rstd * g.y + b.y);
    o.z = f2bf((v[t].z - mu) * rstd * g.z + b.z);
    o.w = f2bf((v[t].w - mu) * rstd * g.w + b.w);
    *reinterpret_cast<ushort4*>(out + row * (long)D + d) = o;
  }
}

// ---------------- LayerNorm bf16-in -> bf16 out (D = 2048) ------------------
__global__ __launch_bounds__(256) void ln_bf16b_k(
    const ushort* __restrict__ in, const float* __restrict__ sc,
    const float* __restrict__ bi, ushort* __restrict__ out)
{
  const long row = blockIdx.x;
  const int tx = threadIdx.x;
  const int d = tx * 8;
  short8 v8 = *reinterpret_cast<const short8*>(in + row * 2048 + d);
  float v[8];
  float s = 0.f, s2 = 0.f;
#pragma unroll
  for (int j = 0; j < 8; ++j) {
    v[j] = bfu2f((ushort)v8[j]);
    s += v[j]; s2 += v[j] * v[j];
  }
#pragma unroll
  for (int o = 1; o < 64; o <<= 1) { s += __shfl_xor(s, o); s2 += __shfl_xor(s2, o); }
  __shared__ float red[2][4];
  const int wave = tx >> 6;
  if ((tx & 63) == 0) { red[0][wave] = s; red[1][wave] = s2; }
  __syncthreads();
  s  = red[0][0] + red[0][1] + red[0][2] + red[0][3];
  s2 = red[1][0] + red[1][1] + red[1][2] + red[1][3];
  const float mu   = s * (1.f / 2048.f);
  const float rstd = rsqrtf(s2 * (1.f / 2048.f) - mu * mu + 1e-6f);
  float4 g0 = *reinterpret_cast<const float4*>(sc + d);
  float4 g1 = *reinterpret_cast<const float4*>(sc + d + 4);
  float4 b0 = *reinterpret_cast<const float4*>(bi + d);
  float4 b1 = *reinterpret_cast<const float4*>(bi + d + 4);
  const float gg[8] = {g0.x, g0.y, g0.z, g0.w, g1.x, g1.y, g1.z, g1.w};
  const float bb[8] = {b0.x, b0.y, b0.z, b0.w, b1.x, b1.y, b1.z, b1.w};
  short8 o8;
#pragma unroll
  for (int j = 0; j < 8; ++j)
    o8[j] = (short)f2bf((v[j] - mu) * rstd * gg[j] + bb[j]);
  *reinterpret_cast<short8*>(out + row * 2048 + d) = o8;
}

// ---------------- fp32 [K][N] -> bf16 [N][K] (transpose + convert) ----------
__global__ __launch_bounds__(256) void transpose_bf16_k(
    const float* __restrict__ in, ushort* __restrict__ out, int K, int N)
{
  __shared__ float tile[64][65];
  const int k0 = blockIdx.y * 64, n0 = blockIdx.x * 64;
  const int tx = threadIdx.x, ty = threadIdx.y;
#pragma unroll
  for (int r = ty; r < 64; r += 4)
    tile[r][tx] = in[(long)(k0 + r) * N + n0 + tx];
  __syncthreads();
#pragma unroll
  for (int r = ty; r < 64; r += 4)
    out[(long)(n0 + r) * K + k0 + tx] = f2bf(tile[tx][r]);
}

// ============================================================================
// 256x256 GEMM, 3 windows/K-tile (6 barriers), B-frag parity rotation:
// next tile's B-frags load in current tile's last window (after the
// vmcnt(6)+barrier that validates their buffer) overlapping the Q10 MFMAs.
// 512 thr = 8 waves (2Mx4N), per-wave 128x64, BK=64, LDS 128 KiB XOR-swizzled.
// MODE 0: h=silu(acc+b) bf16; MODE 1: h+=silu(acc+b) bf16; MODE 2: C=acc+b f32.
// ============================================================================
#define STG(gsrc, ldst)                                                          \
  __builtin_amdgcn_global_load_lds(AS1(gsrc),          AS3(ldst),        16, 0, 0); \
  __builtin_amdgcn_global_load_lds(AS1((gsrc) + offQ), AS3((ldst) + 8192), 16, 0, 0);

#define ldsA(B, H) (ldsW + (B) * 65536 + (H) * 16384)
#define ldsB(B, H) (ldsW + (B) * 65536 + 32768 + (H) * 16384)

#define LOAD_A(dst, DB, ihalf)                                                  \
  _Pragma("unroll") for (int i_ = 0; i_ < 4; ++i_) {                            \
    dst[i_][0] = *(const short8*)(smem + (DB) * 65536 + aOff + ((ihalf) * 4 + i_) * 2048 + rdk0); \
    dst[i_][1] = *(const short8*)(smem + (DB) * 65536 + aOff + ((ihalf) * 4 + i_) * 2048 + rdk1); \
  }

#define LOAD_B(dst, DB, jhalf)                                                  \
  _Pragma("unroll") for (int j_ = 0; j_ < 2; ++j_) {                            \
    dst[j_][0] = *(const short8*)(smem + (DB) * 65536 + bOff + ((jhalf) * 2 + j_) * 2048 + rdk0); \
    dst[j_][1] = *(const short8*)(smem + (DB) * 65536 + bOff + ((jhalf) * 2 + j_) * 2048 + rdk1); \
  }

#define MFMA_Q(ihalf, jhalf, afr, bfr)                                          \
  __builtin_amdgcn_s_setprio(1);                                                \
  _Pragma("unroll") for (int kk_ = 0; kk_ < 2; ++kk_)                           \
  _Pragma("unroll") for (int i_ = 0; i_ < 4; ++i_)                              \
  _Pragma("unroll") for (int j_ = 0; j_ < 2; ++j_)                              \
    acc[(ihalf) * 4 + i_][(jhalf) * 2 + j_] =                                   \
        __builtin_amdgcn_mfma_f32_16x16x32_bf16(afr[i_][kk_], bfr[j_][kk_],     \
            acc[(ihalf) * 4 + i_][(jhalf) * 2 + j_], 0, 0, 0);                  \
  __builtin_amdgcn_s_setprio(0);

// One K-tile, 3 windows. BA = current jhalf0 frags, BB = jhalf1.
// W0: ld A.ih0 | stage A(t+1)h1 | bar | Q00 Q01 | bar
// W1: ld A.ih1 | stage B(t+2)h0 | bar | Q11 | bar
// W2: stage B(t+2)h1 + A(t+2)h0 | vmcnt(6) | bar | Q10 + prefetch next B | bar
#define DO_TILE(CUR, NXT, BA, BB, AO1, AO2, BO2, S0, S2, S3, TAILW, PFB)        \
  LOAD_A(af, CUR, 0);                                                           \
  if (S0) { STG(aP + (AO1) + offH, ldsA(NXT, 1)); }                             \
  __builtin_amdgcn_s_barrier();                                                 \
  MFMA_Q(0, 0, af, BA);                                                         \
  MFMA_Q(0, 1, af, BB);                                                         \
  __builtin_amdgcn_s_barrier();                                                 \
  LOAD_A(af, CUR, 1);                                                           \
  if (S2) { STG(bP + (BO2), ldsB(CUR, 0)); }                                    \
  __builtin_amdgcn_s_barrier();                                                 \
  MFMA_Q(1, 1, af, BB);                                                         \
  __builtin_amdgcn_s_barrier();                                                 \
  if (S3) { STG(bP + (BO2) + offH, ldsB(CUR, 1)); STG(aP + (AO2), ldsA(CUR, 0)); } \
  if (S3)            { asm volatile("s_waitcnt vmcnt(6)" ::: "memory"); }       \
  else if (TAILW)    { asm volatile("s_waitcnt vmcnt(0)" ::: "memory"); }       \
  __builtin_amdgcn_sched_barrier(0);                                            \
  __builtin_amdgcn_s_barrier();                                                 \
  MFMA_Q(1, 0, af, BA);                                                         \
  if (PFB) { LOAD_B(BB, NXT, 0); LOAD_B(BA, NXT, 1); }                          \
  __builtin_amdgcn_s_barrier();

template<int MODE>
__global__ __launch_bounds__(512, 2) void gemm256_k(
    const ushort* __restrict__ A, const ushort* __restrict__ Bt,
    const float* __restrict__ bias, void* __restrict__ Cv,
    int M, int N, int K)
{
  extern __shared__ char smem[];
  const int tid = threadIdx.x;
  const int lane = tid & 63, wid = tid >> 6;
  const int wr = wid >> 2, wc = wid & 3;
  const int nbx = N >> 8;

  // bijective XCD swizzle (grid % 8 == 0 for all shapes here)
  int bid;
  {
    const int b = blockIdx.x;
    const int cpx = gridDim.x >> 3;
    bid = (b & 7) * cpx + (b >> 3);
  }
  const int bx = bid % nbx, by = bid / nbx;
  const long m0 = (long)by << 8, n0 = (long)bx << 8;

  // staging: thread -> (row tid>>3 [+64], inverse-swizzled 16B chunk)
  const int srow = tid >> 3;
  const int scol = (((tid & 7) * 16) ^ (((tid >> 3) & 7) << 4)) >> 1;  // elements
  const ushort* aP = A  + (m0 + srow) * (long)K + scol;
  const ushort* bP = Bt + (n0 + srow) * (long)K + scol;
  const long offH = 128L * K, offQ = 64L * K;
  char* ldsW = smem + wid * 1024;

  // ds_read offsets (bytes); XOR swizzle ((row&7)<<4) == ((lane&7)<<4)
  const int rdk0 = (((lane >> 4) * 16)     ) ^ ((lane & 7) << 4);
  const int rdk1 = (((lane >> 4) * 16) + 64) ^ ((lane & 7) << 4);
  const int aOff = wr * 16384 + (lane & 15) * 128;
  const int bOff = 32768 + (wc >> 1) * 16384 + ((wc & 1) * 64 + (lane & 15)) * 128;

  f32x4 acc[8][4] = {};
  const int NT = K >> 6;  // even, >= 4

  // prologue: 14 loads; vmcnt(6) leaves B(1) + A(1)h0 in flight (steady state)
  STG(aP,           ldsA(0, 0));  STG(aP + offH,      ldsA(0, 1));
  STG(bP,           ldsB(0, 0));  STG(bP + offH,      ldsB(0, 1));
  STG(bP + 64,      ldsB(1, 0));  STG(bP + 64 + offH, ldsB(1, 1));
  STG(aP + 64,      ldsA(1, 0));
  asm volatile("s_waitcnt vmcnt(6)" ::: "memory");
  __builtin_amdgcn_sched_barrier(0);
  __builtin_amdgcn_s_barrier();

  short8 af[4][2], bfA[2][2], bfB[2][2];
  LOAD_B(bfA, 0, 0);
  LOAD_B(bfB, 0, 1);

  for (int t = 0; t < NT - 2; t += 2) {
    DO_TILE(0, 1, bfA, bfB,  64, 128, 128, 1, 1, 1, 0, 1)
    DO_TILE(1, 0, bfB, bfA, 128, 192, 192, 1, 1, 1, 0, 1)
    aP += 128; bP += 128;
  }
  // tail pair: only A(NT-1)h1 still to stage; vmcnt(0) then prefetch last B
  DO_TILE(0, 1, bfA, bfB, 64, 0, 0, 1, 0, 0, 1, 1)
  DO_TILE(1, 0, bfB, bfA,  0, 0, 0, 0, 0, 0, 0, 0)

  // epilogue: C/D layout col=lane&15, row=(lane>>4)*4+reg
#pragma unroll
  for (int j = 0; j < 4; ++j) {
    const long col = n0 + wc * 64 + j * 16 + (lane & 15);
    const float bj = bias[col];
#pragma unroll
    for (int i = 0; i < 8; ++i) {
      const long rowb = m0 + wr * 128 + i * 16 + ((lane >> 4) << 2);
#pragma unroll
      for (int r = 0; r < 4; ++r) {
        const float v = acc[i][j][r] + bj;
        const long idx = (rowb + r) * N + col;
        if (MODE == 0) {
          ((ushort*)Cv)[idx] = f2bf(silu_f(v));
        } else if (MODE == 1) {
          ushort* C = (ushort*)Cv;
          C[idx] = f2bf(bfu2f(C[idx]) + silu_f(v));
        } else {
          ((float*)Cv)[idx] = v;
        }
      }
    }
  }
}

// ---------------------------------------------------------------------------
extern "C" void kernel_launch(void* const* d_in, const int* in_sizes, int n_in,
                              void* d_out, int out_size, void* d_ws, size_t ws_size,
                              hipStream_t stream) {
  const float* x     = (const float*)d_in[0];
  const float* ln1_s = (const float*)d_in[1];
  const float* ln1_b = (const float*)d_in[2];
  const float* w1    = (const float*)d_in[3];
  const float* b1    = (const float*)d_in[4];
  const float* bln_s = (const float*)d_in[5];
  const float* bln_b = (const float*)d_in[6];
  const float* bws   = (const float*)d_in[7];
  const float* bbs   = (const float*)d_in[8];
  const float* ln2_s = (const float*)d_in[9];
  const float* ln2_b = (const float*)d_in[10];
  const float* w2    = (const float*)d_in[11];
  const float* b2    = (const float*)d_in[12];
  float* out = (float*)d_out;

  const int M = 8192;
  char* ws = (char*)d_ws;
  ushort* h   = (ushort*)ws;                                  // 8192x2048 bf16 = 32MB
  ushort* Abf = (ushort*)(ws + 33554432);                     // 8192x2048 bf16 = 32MB
  ushort* wt  = (ushort*)(ws + 67108864);                     // bf16 weights^T, 56MB
  const long W1T = 0;                        // [2048][1024]
  const long BLK = 2097152;                  // 6 x [2048][2048]
  const long W2T = BLK + 6L * 4194304;       // [1024][2048]

  (void)hipFuncSetAttribute((const void*)gemm256_k<0>,
      hipFuncAttributeMaxDynamicSharedMemorySize, 131072);
  (void)hipFuncSetAttribute((const void*)gemm256_k<1>,
      hipFuncAttributeMaxDynamicSharedMemorySize, 131072);
  (void)hipFuncSetAttribute((const void*)gemm256_k<2>,
      hipFuncAttributeMaxDynamicSharedMemorySize, 131072);

  dim3 tb(64, 4);
  transpose_bf16_k<<<dim3(2048 / 64, 1024 / 64), tb, 0, stream>>>(w1, wt + W1T, 1024, 2048);
  for (int i = 0; i < 6; ++i)
    transpose_bf16_k<<<dim3(32, 32), tb, 0, stream>>>(
        bws + (long)i * 2048 * 2048, wt + BLK + (long)i * 4194304, 2048, 2048);
  transpose_bf16_k<<<dim3(1024 / 64, 2048 / 64), tb, 0, stream>>>(w2, wt + W2T, 2048, 1024);

  // stem: h = silu(LN(x) @ w1 + b1)   (h bf16)
  ln_bf16_k<1><<<M, 256, 0, stream>>>(x, ln1_s, ln1_b, Abf);
  gemm256_k<0><<<32 * 8, 512, 131072, stream>>>(Abf, wt + W1T, b1, (void*)h, M, 2048, 1024);

  // residual blocks: h = h + silu(LN(h) @ w[i] + lb[i])
  for (int i = 0; i < 6; ++i) {
    ln_bf16b_k<<<M, 256, 0, stream>>>(h, bln_s + i * 2048, bln_b + i * 2048, Abf);
    gemm256_k<1><<<32 * 8, 512, 131072, stream>>>(
        Abf, wt + BLK + (long)i * 4194304, bbs + i * 2048, (void*)h, M, 2048, 2048);
  }

  // head: out = LN(h) @ w2 + b2
  ln_bf16b_k<<<M, 256, 0, stream>>>(h, ln2_s, ln2_b, Abf);
  gemm256_k<2><<<32 * 4, 512, 131072, stream>>>(Abf, wt + W2T, b2, (void*)out, M, 1024, 2048);
}